// Round 2
// 169.357 us; speedup vs baseline: 1.0566x; 1.0566x over previous
//
#include <hip/hip_runtime.h>
#include <hip/hip_bf16.h>
#include <stdint.h>

// OFPenalty: per-batch Gram (49x49 from 2048x49) -> two 9-step power
// iterations -> penalty scalar. Memory-bound on reading x (102.8 MB; floor
// ~16.3 us at 6.3 TB/s). Timed region also contains ~2 harness workspace
// poison fills (~60 us each, 392 MiB) we cannot control from here.
//
// R3 = R2 resubmission (container infra failure, no counters). Only change:
// union uses a trivial ext_vector float4 alias instead of HIP float4 to
// remove any constructor-in-union compile risk.
//
// R2 changes vs R1:
//  - gram: split-bf16 conversion done ONCE per element at staging (was 4x,
//    once per consuming wave) and stored TRANSPOSED [n][k] in LDS as hi/lo
//    bf16 with a 16B-block XOR swizzle (blk ^= n&7). Fragment loads become
//    one ds_read_b128 per MFMA operand (was 8 scalar ds_read_b32 + cvt per
//    operand). Reg-staged global loads (8 coalesced dwords/thread/chunk),
//    double-buffered LDS, one barrier per chunk. K-order and conversion math
//    bit-identical to R1 -> identical Gram output.
//  - eigen: 256 threads; float4 quarter-sum (partial stride padded to 2404
//    for 16B alignment); A row cached in 49 VGPRs per lane; 4-accumulator
//    dot breaks the serial fma chain. Waves 1-3 compute redundantly; wave 0
//    owns xv writes.

#define BATCH 256
#define CDIM  2048
#define NDIM  49
#define QK    512                    // C rows per block (2048/4)
#define NQ    4                      // C quarters
#define CHUNK 64                     // k rows per LDS stage
#define NCHUNK (QK / CHUNK)          // 8
#define ITEMS (NDIM * (CHUNK / 8))   // 392 16B k-blocks per chunk
#define PSTRIDE 2404                 // 49*49=2401 padded to multiple of 4

typedef __bf16 bf16x8 __attribute__((ext_vector_type(8)));
typedef float  f32x16 __attribute__((ext_vector_type(16)));
typedef float  f32x4  __attribute__((ext_vector_type(4)));

union V16 {
  f32x4  f4;
  bf16x8 b8;
};

__device__ __forceinline__ void load8(const float* __restrict__ g,
                                      float (&r)[8]) {
#pragma unroll
  for (int j = 0; j < 8; ++j) r[j] = g[j * NDIM];
}

__device__ __forceinline__ void cvt_store(const float (&r)[8], uint32_t* Hb,
                                          uint32_t* Lb, int w) {
  bf16x8 hv, lv;
#pragma unroll
  for (int j = 0; j < 8; ++j) {
    float e = r[j];
    __bf16 h = (__bf16)e;            // RNE high part
    hv[j] = h;
    lv[j] = (__bf16)(e - (float)h);  // exact residual, then RNE
  }
  V16 a, b;
  a.b8 = hv;
  b.b8 = lv;
  *(f32x4*)(Hb + w) = a.f4;   // ds_write_b128, swizzled slot
  *(f32x4*)(Lb + w) = b.f4;
}

__device__ __forceinline__ void comp16(const uint32_t* Hb, const uint32_t* Lb,
                                       int m, int n, int hf, f32x16& c1,
                                       f32x16& c2, f32x16& c3) {
  const f32x4* H = (const f32x4*)Hb;
  const f32x4* L = (const f32x4*)Lb;
#pragma unroll
  for (int s = 0; s < 4; ++s) {
    const int blk = 2 * s + hf;   // k-halves: kk = s*16 + hf*8
    V16 ah, al, bh, bl;
    ah.f4 = H[m * 8 + (blk ^ (m & 7))];
    al.f4 = L[m * 8 + (blk ^ (m & 7))];
    bh.f4 = H[n * 8 + (blk ^ (n & 7))];
    bl.f4 = L[n * 8 + (blk ^ (n & 7))];
    c1 = __builtin_amdgcn_mfma_f32_32x32x16_bf16(ah.b8, bh.b8, c1, 0, 0, 0);
    c2 = __builtin_amdgcn_mfma_f32_32x32x16_bf16(ah.b8, bl.b8, c2, 0, 0, 0);
    c3 = __builtin_amdgcn_mfma_f32_32x32x16_bf16(al.b8, bh.b8, c3, 0, 0, 0);
  }
}

__global__ __launch_bounds__(256, 4) void gram_kernel(
    const float* __restrict__ x, float* __restrict__ partial,
    float* __restrict__ out) {
  // Transposed split-bf16 chunk: row n (0..48, rows 49-63 stale/ignored),
  // 64 bf16 along k = 8 16B-blocks, block index XOR-swizzled by (n&7).
  // Reads: uniform 8-way b128 aliasing (optimal). Writes: 64 distinct
  // (n,blk') slots, uniform across banks.
  __shared__ __align__(16) uint32_t ldsHi[2][2048];  // 8 KB per buffer
  __shared__ __align__(16) uint32_t ldsLo[2][2048];

  const int tid  = threadIdx.x;
  const int bidx = blockIdx.x;        // 0..1023
  const int batch = bidx >> 2;
  const int q     = bidx & 3;
  const int lane = tid & 63;
  const int wv   = tid >> 6;          // 0..3
  const int ln   = lane & 31;
  const int hf   = lane >> 5;         // k-half selector
  const int qm = wv >> 1, qn = wv & 1;
  const int m = qm * 32 + ln;         // A row this lane feeds
  const int n = qn * 32 + ln;         // B col this lane feeds

  if (bidx == 0 && tid == 0) out[0] = 0.f;  // replaces memset dispatch

  const float* gbase = x + (size_t)batch * (CDIM * NDIM)
                         + (size_t)q * (QK * NDIM);

  // staging item assignment (constant across chunks): item = kq*49 + n_s
  const int i0 = tid;                       // always < 392
  const int i1 = tid + 256;
  const bool v1 = (i1 < ITEMS);             // tid < 136
  const int kq0 = (i0 * 1338) >> 16;        // exact /49 for i < 2520
  const int n0  = i0 - 49 * kq0;
  const int kq1 = (i1 * 1338) >> 16;
  const int n1  = i1 - 49 * kq1;
  const int g0  = kq0 * (8 * NDIM) + n0;    // float offset of (k=8*kq, n)
  const int g1  = kq1 * (8 * NDIM) + n1;
  const int w0  = n0 * 32 + 4 * (kq0 ^ (n0 & 7));  // u32 slot (swizzled)
  const int w1  = n1 * 32 + 4 * (kq1 ^ (n1 & 7));

  f32x16 c1, c2, c3;
#pragma unroll
  for (int i = 0; i < 16; ++i) { c1[i] = 0.f; c2[i] = 0.f; c3[i] = 0.f; }

  float sA0[8], sA1[8], sB0[8], sB1[8];

  // prologue: chunk 0 -> regs
  load8(gbase + g0, sA0);
  if (v1) load8(gbase + g1, sA1);

#pragma unroll
  for (int ch = 0; ch < NCHUNK; ch += 2) {
    {  // prefetch chunk ch+1 (hides HBM latency under cvt+barrier+compute)
      const float* gch = gbase + (size_t)(ch + 1) * (CHUNK * NDIM);
      load8(gch + g0, sB0);
      if (v1) load8(gch + g1, sB1);
    }
    cvt_store(sA0, ldsHi[0], ldsLo[0], w0);
    if (v1) cvt_store(sA1, ldsHi[0], ldsLo[0], w1);
    __syncthreads();  // buf0 ready; everyone done reading buf1 (prev iter)
    comp16(ldsHi[0], ldsLo[0], m, n, hf, c1, c2, c3);

    if (ch + 2 < NCHUNK) {
      const float* gch = gbase + (size_t)(ch + 2) * (CHUNK * NDIM);
      load8(gch + g0, sA0);
      if (v1) load8(gch + g1, sA1);
    }
    cvt_store(sB0, ldsHi[1], ldsLo[1], w0);
    if (v1) cvt_store(sB1, ldsHi[1], ldsLo[1], w1);
    __syncthreads();  // buf1 ready; everyone done reading buf0
    comp16(ldsHi[1], ldsLo[1], m, n, hf, c1, c2, c3);
  }

  // C/D layout (m74/m101): col = lane&31, row = (reg&3) + 8*(reg>>2) + 4*(lane>>5)
  float* outp = partial + (size_t)bidx * PSTRIDE;
#pragma unroll
  for (int r = 0; r < 16; ++r) {
    int row = (r & 3) + 8 * (r >> 2) + 4 * hf;
    int mm = qm * 32 + row;
    if (mm < NDIM && n < NDIM)
      outp[mm * NDIM + n] = c1[r] + c2[r] + c3[r];
  }
}

__global__ __launch_bounds__(256) void eigen_kernel(
    const float* __restrict__ partial, const float* __restrict__ x0,
    float* __restrict__ out) {
  __shared__ __align__(16) float A[NDIM * NDIM + 3];  // flat 49x49
  __shared__ float xv[NDIM];

  const int b  = blockIdx.x;
  const int t  = threadIdx.x;  // 0..255
  const int ln = t & 63;
  const float* p0 = partial + (size_t)(NQ * b) * PSTRIDE;

  // quarter-sum, float4-vectorized (PSTRIDE keeps quarters 16B-aligned)
  const f32x4* q0 = (const f32x4*)(p0);
  const f32x4* q1 = (const f32x4*)(p0 + PSTRIDE);
  const f32x4* q2 = (const f32x4*)(p0 + 2 * PSTRIDE);
  const f32x4* q3 = (const f32x4*)(p0 + 3 * PSTRIDE);
  for (int i = t; i < 600; i += 256) {
    f32x4 s = q0[i] + q1[i] + q2[i] + q3[i];
    ((f32x4*)A)[i] = s;
  }
  if (t == 0)
    A[2400] = p0[2400] + p0[PSTRIDE + 2400] + p0[2 * PSTRIDE + 2400] +
              p0[3 * PSTRIDE + 2400];
  if (t < NDIM) xv[t] = x0[b * NDIM + t];
  __syncthreads();

  // each lane caches its A row in registers (rows 49..63 aliased to 48,
  // results masked by `act`)
  float Ar[NDIM];
  {
    const float* Arow = &A[((ln < NDIM) ? ln : (NDIM - 1)) * NDIM];
#pragma unroll
    for (int k = 0; k < NDIM; ++k) Ar[k] = Arow[k];
  }
  const bool act = (ln < NDIM);

  // Replicates _dominant_eigenvalue: 9x {x = normalize((A - sI) x)}, then
  // Rayleigh num/den on one more matvec. All 4 waves compute redundantly
  // (identical inputs -> identical results); wave 0 (t<49) owns xv writes.
  auto rayleigh = [&](float shift) -> float {
    for (int it = 0; it < 9; ++it) {
      float a0 = 0.f, a1 = 0.f, a2 = 0.f, a3 = 0.f;
#pragma unroll
      for (int k = 0; k < 48; k += 4) {
        a0 = fmaf(Ar[k + 0], xv[k + 0], a0);
        a1 = fmaf(Ar[k + 1], xv[k + 1], a1);
        a2 = fmaf(Ar[k + 2], xv[k + 2], a2);
        a3 = fmaf(Ar[k + 3], xv[k + 3], a3);
      }
      a0 = fmaf(Ar[48], xv[48], a0);
      float xvl = act ? xv[ln] : 0.f;
      float y = act ? (((a0 + a1) + (a2 + a3)) - shift * xvl) : 0.f;
      float s2 = y * y;
#pragma unroll
      for (int o = 32; o; o >>= 1) s2 += __shfl_xor(s2, o, 64);
      float nrm = fmaxf(sqrtf(s2), 1e-12f);  // F.normalize eps
      float xn = y / nrm;
      __syncthreads();              // all waves done reading old xv
      if (t < NDIM) xv[t] = xn;     // single writer (wave 0, t==ln)
      __syncthreads();
    }
    float a0 = 0.f, a1 = 0.f, a2 = 0.f, a3 = 0.f;
#pragma unroll
    for (int k = 0; k < 48; k += 4) {
      a0 = fmaf(Ar[k + 0], xv[k + 0], a0);
      a1 = fmaf(Ar[k + 1], xv[k + 1], a1);
      a2 = fmaf(Ar[k + 2], xv[k + 2], a2);
      a3 = fmaf(Ar[k + 3], xv[k + 3], a3);
    }
    a0 = fmaf(Ar[48], xv[48], a0);
    float xvl = act ? xv[ln] : 0.f;
    float yy = act ? (((a0 + a1) + (a2 + a3)) - shift * xvl) : 0.f;
    float num = yy * xvl;
    float den = xvl * xvl;
#pragma unroll
    for (int o = 32; o; o >>= 1) {
      num += __shfl_xor(num, o, 64);
      den += __shfl_xor(den, o, 64);
    }
    return num / den;
  };

  float largest  = rayleigh(0.f);
  float tmp      = rayleigh(largest);  // warm start: xv == x1 already
  float smallest = tmp + largest;

  if (t == 0) {
    float r = largest / smallest - 1.f;
    atomicAdd(out, r * r * (1.0f / (float)BATCH));  // BETA = 1
  }
}

extern "C" void kernel_launch(void* const* d_in, const int* in_sizes, int n_in,
                              void* d_out, int out_size, void* d_ws,
                              size_t ws_size, hipStream_t stream) {
  const float* x  = (const float*)d_in[0];   // [256,2048,7,7] fp32
  const float* x0 = (const float*)d_in[1];   // [256,49,1] fp32 (pre-normalized)
  float* out = (float*)d_out;                // scalar fp32
  float* partial = (float*)d_ws;             // 1024 * 2404 fp32 = 9.85 MB

  gram_kernel<<<1024, 256, 0, stream>>>(x, partial, out);
  eigen_kernel<<<BATCH, 256, 0, stream>>>(partial, x0, out);
}